// Round 1
// baseline (222.412 us; speedup 1.0000x reference)
//
#include <hip/hip_runtime.h>

// ---- problem constants ----
#define T_SEQ 2048
#define D_MODEL 1024
#define N_HEADS 16
#define D_HEAD 64
#define M_ROWS 4096   // B*T
#define N_QKV 3072
#define K_DIM 1024

typedef __attribute__((ext_vector_type(8))) __bf16 bf16x8;
typedef __attribute__((ext_vector_type(4))) __bf16 bf16x4;
typedef __attribute__((ext_vector_type(2))) __bf16 bf16x2;
typedef __attribute__((ext_vector_type(4))) float f32x4;

#define NEG_INF (-__builtin_inff())

// ---------------- f32 -> bf16 convert ----------------
__global__ __launch_bounds__(256) void cvt_f32_bf16(const float* __restrict__ in,
                                                    __bf16* __restrict__ out, int n4) {
  int i = blockIdx.x * 256 + threadIdx.x;
  if (i >= n4) return;
  float4 f = reinterpret_cast<const float4*>(in)[i];
  bf16x4 o;
  o[0] = (__bf16)f.x; o[1] = (__bf16)f.y; o[2] = (__bf16)f.z; o[3] = (__bf16)f.w;
  reinterpret_cast<bf16x4*>(out)[i] = o;
}

// ---------------- QKV GEMM: C = A @ W^T + bias, scatter to q/k/vT ----------------
// A [M_ROWS][K_DIM] bf16, W [N_QKV][K_DIM] bf16.
// q,k -> (BH, T, DK) bf16 ; v -> (BH, DK, T) bf16 (transposed for attention B-frags)
__global__ __launch_bounds__(256) void gemm_qkv(
    const __bf16* __restrict__ A, const __bf16* __restrict__ W,
    const float* __restrict__ bias,
    __bf16* __restrict__ qb, __bf16* __restrict__ kb, __bf16* __restrict__ vtb) {
  __shared__ __bf16 As[128][72];   // +8 pad: 2-way LDS aliasing only (free)
  __shared__ __bf16 Bs[128][72];
  const int bm = blockIdx.y * 128, bn = blockIdx.x * 128;
  const int tid = threadIdx.x;
  const int w = tid >> 6, l = tid & 63;
  const int wr = w >> 1, wc = w & 1;
  const int l15 = l & 15, lg = l >> 4;
  f32x4 acc[4][4] = {};
  for (int k0 = 0; k0 < K_DIM; k0 += 64) {
#pragma unroll
    for (int p = 0; p < 4; ++p) {
      int flat = p * 256 + tid;
      int row = flat >> 3, cb = (flat & 7) * 8;
      *reinterpret_cast<bf16x8*>(&As[row][cb]) =
          *reinterpret_cast<const bf16x8*>(&A[(size_t)(bm + row) * K_DIM + k0 + cb]);
      *reinterpret_cast<bf16x8*>(&Bs[row][cb]) =
          *reinterpret_cast<const bf16x8*>(&W[(size_t)(bn + row) * K_DIM + k0 + cb]);
    }
    __syncthreads();
#pragma unroll
    for (int kk = 0; kk < 2; ++kk) {
      bf16x8 af[4], bfr[4];
#pragma unroll
      for (int i = 0; i < 4; ++i)
        af[i] = *reinterpret_cast<const bf16x8*>(&As[wr * 64 + i * 16 + l15][kk * 32 + lg * 8]);
#pragma unroll
      for (int j = 0; j < 4; ++j)
        bfr[j] = *reinterpret_cast<const bf16x8*>(&Bs[wc * 64 + j * 16 + l15][kk * 32 + lg * 8]);
#pragma unroll
      for (int i = 0; i < 4; ++i)
#pragma unroll
        for (int j = 0; j < 4; ++j)
          acc[i][j] = __builtin_amdgcn_mfma_f32_16x16x32_bf16(af[i], bfr[j], acc[i][j], 0, 0, 0);
    }
    __syncthreads();
  }
  // epilogue: C/D layout row=(lg*4+r), col=l15  [m89-verified]
#pragma unroll
  for (int i = 0; i < 4; ++i)
#pragma unroll
    for (int j = 0; j < 4; ++j) {
      int n = bn + wc * 64 + j * 16 + l15;
      float bv = bias[n];
      int which = n >> 10, d = n & 1023;
      int h = d >> 6, dk = d & 63;
#pragma unroll
      for (int r = 0; r < 4; ++r) {
        int m = bm + wr * 64 + i * 16 + lg * 4 + r;
        int b = m >> 11, t = m & 2047;
        float v = acc[i][j][r] + bv;
        int bh = b * N_HEADS + h;
        if (which == 0)      qb[((size_t)bh * T_SEQ + t) * D_HEAD + dk] = (__bf16)v;
        else if (which == 1) kb[((size_t)bh * T_SEQ + t) * D_HEAD + dk] = (__bf16)v;
        else                 vtb[((size_t)bh * D_HEAD + dk) * T_SEQ + t] = (__bf16)v;
      }
    }
}

// ---------------- output GEMM: out = A @ W^T + bias (f32 out) ----------------
__global__ __launch_bounds__(256) void gemm_out(
    const __bf16* __restrict__ A, const __bf16* __restrict__ W,
    const float* __restrict__ bias, float* __restrict__ out) {
  __shared__ __bf16 As[128][72];
  __shared__ __bf16 Bs[128][72];
  const int bm = blockIdx.y * 128, bn = blockIdx.x * 128;
  const int tid = threadIdx.x;
  const int w = tid >> 6, l = tid & 63;
  const int wr = w >> 1, wc = w & 1;
  const int l15 = l & 15, lg = l >> 4;
  f32x4 acc[4][4] = {};
  for (int k0 = 0; k0 < K_DIM; k0 += 64) {
#pragma unroll
    for (int p = 0; p < 4; ++p) {
      int flat = p * 256 + tid;
      int row = flat >> 3, cb = (flat & 7) * 8;
      *reinterpret_cast<bf16x8*>(&As[row][cb]) =
          *reinterpret_cast<const bf16x8*>(&A[(size_t)(bm + row) * K_DIM + k0 + cb]);
      *reinterpret_cast<bf16x8*>(&Bs[row][cb]) =
          *reinterpret_cast<const bf16x8*>(&W[(size_t)(bn + row) * K_DIM + k0 + cb]);
    }
    __syncthreads();
#pragma unroll
    for (int kk = 0; kk < 2; ++kk) {
      bf16x8 af[4], bfr[4];
#pragma unroll
      for (int i = 0; i < 4; ++i)
        af[i] = *reinterpret_cast<const bf16x8*>(&As[wr * 64 + i * 16 + l15][kk * 32 + lg * 8]);
#pragma unroll
      for (int j = 0; j < 4; ++j)
        bfr[j] = *reinterpret_cast<const bf16x8*>(&Bs[wc * 64 + j * 16 + l15][kk * 32 + lg * 8]);
#pragma unroll
      for (int i = 0; i < 4; ++i)
#pragma unroll
        for (int j = 0; j < 4; ++j)
          acc[i][j] = __builtin_amdgcn_mfma_f32_16x16x32_bf16(af[i], bfr[j], acc[i][j], 0, 0, 0);
    }
    __syncthreads();
  }
#pragma unroll
  for (int i = 0; i < 4; ++i)
#pragma unroll
    for (int j = 0; j < 4; ++j) {
      int n = bn + wc * 64 + j * 16 + l15;
      float bv = bias[n];
#pragma unroll
      for (int r = 0; r < 4; ++r) {
        int m = bm + wr * 64 + i * 16 + lg * 4 + r;
        out[(size_t)m * D_MODEL + n] = acc[i][j][r] + bv;
      }
    }
}

// ---------------- in-place RoPE on q,k (BH,T,DK) ----------------
__global__ __launch_bounds__(256) void rope_qk(__bf16* __restrict__ qb, __bf16* __restrict__ kb,
                                               const float* __restrict__ fc,
                                               const float* __restrict__ fs) {
  int idx = blockIdx.x * 256 + threadIdx.x;  // [0, BH*T*32), pair id
  int i = idx & 31;
  int t = (idx >> 5) & (T_SEQ - 1);
  float c = fc[t * 32 + i], s = fs[t * 32 + i];
  bf16x2* qp = reinterpret_cast<bf16x2*>(qb);
  bf16x2* kp = reinterpret_cast<bf16x2*>(kb);
  bf16x2 qv = qp[idx];
  float qre = (float)qv[0], qim = (float)qv[1];
  qv[0] = (__bf16)(qre * c - qim * s);
  qv[1] = (__bf16)(qre * s + qim * c);
  qp[idx] = qv;
  bf16x2 kv = kp[idx];
  float kre = (float)kv[0], kim = (float)kv[1];
  kv[0] = (__bf16)(kre * c - kim * s);
  kv[1] = (__bf16)(kre * s + kim * c);
  kp[idx] = kv;
}

// ---------------- causal flash attention ----------------
// grid (T/64, BH). 4 waves; wave w owns q rows [q0+16w, q0+16w+16).
// q,k (BH,T,DK) bf16; v (BH,DK,T) bf16 transposed. out -> (B,T,D) bf16.
__global__ __launch_bounds__(256) void attn_fwd(
    const __bf16* __restrict__ qb, const __bf16* __restrict__ kb,
    const __bf16* __restrict__ vtb, __bf16* __restrict__ ob) {
  __shared__ __bf16 Ks[64][72];       // [key][dk]
  __shared__ __bf16 Vs[64][72];       // [dk][key]
  __shared__ __bf16 Ps[4][16][72];    // per-wave P tile [qrow][key]
  const int qt = blockIdx.x, bh = blockIdx.y;
  const int q0 = qt * 64;
  const int tid = threadIdx.x;
  const int w = tid >> 6, l = tid & 63;
  const int l15 = l & 15, lg = l >> 4;

  bf16x8 aq[2];
  {
    const size_t qbase = ((size_t)bh * T_SEQ + q0 + w * 16 + l15) * D_HEAD;
    aq[0] = *reinterpret_cast<const bf16x8*>(&qb[qbase + lg * 8]);
    aq[1] = *reinterpret_cast<const bf16x8*>(&qb[qbase + 32 + lg * 8]);
  }
  f32x4 o[4] = {};
  float mrow[4] = {NEG_INF, NEG_INF, NEG_INF, NEG_INF};
  float lrow[4] = {0.f, 0.f, 0.f, 0.f};

  for (int t0 = 0; t0 <= q0; t0 += 64) {
#pragma unroll
    for (int p = 0; p < 2; ++p) {
      int flat = p * 256 + tid;
      int row = flat >> 3, cb = (flat & 7) * 8;
      *reinterpret_cast<bf16x8*>(&Ks[row][cb]) =
          *reinterpret_cast<const bf16x8*>(&kb[((size_t)bh * T_SEQ + t0 + row) * D_HEAD + cb]);
      *reinterpret_cast<bf16x8*>(&Vs[row][cb]) =
          *reinterpret_cast<const bf16x8*>(&vtb[((size_t)bh * D_HEAD + row) * T_SEQ + t0 + cb]);
    }
    __syncthreads();

    // S = Q K^T
    f32x4 s[4] = {};
#pragma unroll
    for (int kk = 0; kk < 2; ++kk) {
#pragma unroll
      for (int cb = 0; cb < 4; ++cb) {
        bf16x8 bfrag = *reinterpret_cast<const bf16x8*>(&Ks[cb * 16 + l15][kk * 32 + lg * 8]);
        s[cb] = __builtin_amdgcn_mfma_f32_16x16x32_bf16(aq[kk], bfrag, s[cb], 0, 0, 0);
      }
    }

    // scale + causal mask + online softmax (D layout: row=lg*4+r, col=l15+16cb)
    float pm[4][4];
    float rmax[4];
#pragma unroll
    for (int r = 0; r < 4; ++r) {
      int qrow = q0 + w * 16 + lg * 4 + r;
      float mx = NEG_INF;
#pragma unroll
      for (int cb = 0; cb < 4; ++cb) {
        int key = t0 + cb * 16 + l15;
        float v = s[cb][r] * 0.125f;
        if (key > qrow) v = NEG_INF;
        pm[cb][r] = v;
        mx = fmaxf(mx, v);
      }
      rmax[r] = mx;
    }
#pragma unroll
    for (int d = 1; d < 16; d <<= 1)
#pragma unroll
      for (int r = 0; r < 4; ++r)
        rmax[r] = fmaxf(rmax[r], __shfl_xor(rmax[r], d));
    float fac[4], rs[4];
#pragma unroll
    for (int r = 0; r < 4; ++r) {
      float mnew = fmaxf(mrow[r], rmax[r]);
      fac[r] = __expf(mrow[r] - mnew);  // -inf - finite -> 0 on first tile
      mrow[r] = mnew;
      float sum = 0.f;
#pragma unroll
      for (int cb = 0; cb < 4; ++cb) {
        float p = __expf(pm[cb][r] - mnew);
        pm[cb][r] = p;
        sum += p;
      }
      rs[r] = sum;
    }
#pragma unroll
    for (int d = 1; d < 16; d <<= 1)
#pragma unroll
      for (int r = 0; r < 4; ++r)
        rs[r] += __shfl_xor(rs[r], d);
#pragma unroll
    for (int r = 0; r < 4; ++r)
      lrow[r] = lrow[r] * fac[r] + rs[r];
#pragma unroll
    for (int db = 0; db < 4; ++db)
#pragma unroll
      for (int r = 0; r < 4; ++r)
        o[db][r] *= fac[r];

    // P -> LDS (bf16) to re-fragment for PV (same-wave DS ordering is in-order)
#pragma unroll
    for (int cb = 0; cb < 4; ++cb)
#pragma unroll
      for (int r = 0; r < 4; ++r)
        Ps[w][lg * 4 + r][cb * 16 + l15] = (__bf16)pm[cb][r];

    // O += P V
#pragma unroll
    for (int kk = 0; kk < 2; ++kk) {
      bf16x8 afrag = *reinterpret_cast<const bf16x8*>(&Ps[w][l15][kk * 32 + lg * 8]);
#pragma unroll
      for (int db = 0; db < 4; ++db) {
        bf16x8 bfrag = *reinterpret_cast<const bf16x8*>(&Vs[db * 16 + l15][kk * 32 + lg * 8]);
        o[db] = __builtin_amdgcn_mfma_f32_16x16x32_bf16(afrag, bfrag, o[db], 0, 0, 0);
      }
    }
    __syncthreads();
  }

  const int b = bh >> 4, h = bh & 15;
#pragma unroll
  for (int db = 0; db < 4; ++db)
#pragma unroll
    for (int r = 0; r < 4; ++r) {
      int t = q0 + w * 16 + lg * 4 + r;
      int col = h * 64 + db * 16 + l15;
      ob[((size_t)b * T_SEQ + t) * D_MODEL + col] = (__bf16)(o[db][r] / lrow[r]);
    }
}

extern "C" void kernel_launch(void* const* d_in, const int* in_sizes, int n_in,
                              void* d_out, int out_size, void* d_ws, size_t ws_size,
                              hipStream_t stream) {
  const float* x     = (const float*)d_in[0];
  const float* w_qkv = (const float*)d_in[1];
  const float* b_qkv = (const float*)d_in[2];
  const float* w_out = (const float*)d_in[3];
  const float* b_out = (const float*)d_in[4];
  const float* fc    = (const float*)d_in[5];
  const float* fs    = (const float*)d_in[6];
  float* out = (float*)d_out;
  char* ws = (char*)d_ws;

  // ws layout (bytes): xb 8MiB | wqkvb 6MiB | woutb 2MiB | q 8MiB | k 8MiB | vT 8MiB
  __bf16* xb    = (__bf16*)(ws);
  __bf16* wqkvb = (__bf16*)(ws + 8388608);
  __bf16* woutb = (__bf16*)(ws + 14680064);
  __bf16* qbuf  = (__bf16*)(ws + 16777216);
  __bf16* kbuf  = (__bf16*)(ws + 25165824);
  __bf16* vtbuf = (__bf16*)(ws + 33554432);
  __bf16* attnb = xb;  // xb dead after gemm_qkv; reuse for attention output

  cvt_f32_bf16<<<4096, 256, 0, stream>>>(x, xb, 1048576);
  cvt_f32_bf16<<<3072, 256, 0, stream>>>(w_qkv, wqkvb, 786432);
  cvt_f32_bf16<<<1024, 256, 0, stream>>>(w_out, woutb, 262144);
  gemm_qkv<<<dim3(24, 32), 256, 0, stream>>>(xb, wqkvb, b_qkv, qbuf, kbuf, vtbuf);
  rope_qk<<<8192, 256, 0, stream>>>(qbuf, kbuf, fc, fs);
  attn_fwd<<<dim3(32, 32), 256, 0, stream>>>(qbuf, kbuf, vtbuf, attnb);
  gemm_out<<<dim3(8, 32), 256, 0, stream>>>(attnb, woutb, b_out, out);
}

// Round 2
// 185.018 us; speedup vs baseline: 1.2021x; 1.2021x over previous
//
#include <hip/hip_runtime.h>

// ---- problem constants ----
#define T_SEQ 2048
#define D_MODEL 1024
#define N_HEADS 16
#define D_HEAD 64
#define NT 32          // T_SEQ / 64
#define K_DIM 1024

typedef __attribute__((ext_vector_type(8))) __bf16 bf16x8;
typedef __attribute__((ext_vector_type(4))) __bf16 bf16x4;
typedef __attribute__((ext_vector_type(2))) __bf16 bf16x2;
typedef __attribute__((ext_vector_type(4))) float f32x4;

#define SCL_LOG2 0.180336880f  // 0.125 * log2(e)
#define MASKVAL (-1e30f)

#define GLOAD_LDS16(g, l)                                                     \
  __builtin_amdgcn_global_load_lds(                                           \
      (const __attribute__((address_space(1))) void*)(g),                     \
      (__attribute__((address_space(3))) void*)(l), 16, 0, 0)

// ---------------- f32 -> bf16 convert ----------------
__global__ __launch_bounds__(256) void cvt_f32_bf16(const float* __restrict__ in,
                                                    __bf16* __restrict__ out, int n4) {
  int i = blockIdx.x * 256 + threadIdx.x;
  if (i >= n4) return;
  float4 f = reinterpret_cast<const float4*>(in)[i];
  bf16x4 o;
  o[0] = (__bf16)f.x; o[1] = (__bf16)f.y; o[2] = (__bf16)f.z; o[3] = (__bf16)f.w;
  reinterpret_cast<bf16x4*>(out)[i] = o;
}

// ---------------- QKV GEMM (m97 structure): C = A @ W^T + bias, scatter ----------------
__global__ __launch_bounds__(256) void gemm_qkv(
    const __bf16* __restrict__ A, const __bf16* __restrict__ W,
    const float* __restrict__ bias,
    __bf16* __restrict__ qb, __bf16* __restrict__ kb, __bf16* __restrict__ vtb) {
  __shared__ __bf16 As[128 * 64];
  __shared__ __bf16 Bs[128 * 64];
  const int bm = blockIdx.y * 128, bn = blockIdx.x * 128;
  const int tid = threadIdx.x;
  const int w = tid >> 6, l = tid & 63;
  const int wr = w >> 1, wc = w & 1;
  const int l15 = l & 15, lg = l >> 4;
  const int srow = w * 32 + (l >> 3);   // + q*8
  const int scol = (l & 7) * 8;
  f32x4 acc[4][4] = {};
  for (int k0 = 0; k0 < K_DIM; k0 += 64) {
#pragma unroll
    for (int q = 0; q < 4; ++q) {
      GLOAD_LDS16(&A[(size_t)(bm + srow + q * 8) * K_DIM + k0 + scol], &As[(w * 32 + q * 8) * 64]);
      GLOAD_LDS16(&W[(size_t)(bn + srow + q * 8) * K_DIM + k0 + scol], &Bs[(w * 32 + q * 8) * 64]);
    }
    __syncthreads();
#pragma unroll
    for (int kk = 0; kk < 2; ++kk) {
      bf16x8 af[4], bfr[4];
#pragma unroll
      for (int i = 0; i < 4; ++i)
        af[i] = *reinterpret_cast<const bf16x8*>(&As[(wr * 64 + i * 16 + l15) * 64 + kk * 32 + lg * 8]);
#pragma unroll
      for (int j = 0; j < 4; ++j)
        bfr[j] = *reinterpret_cast<const bf16x8*>(&Bs[(wc * 64 + j * 16 + l15) * 64 + kk * 32 + lg * 8]);
      __builtin_amdgcn_s_setprio(1);
#pragma unroll
      for (int i = 0; i < 4; ++i)
#pragma unroll
        for (int j = 0; j < 4; ++j)
          acc[i][j] = __builtin_amdgcn_mfma_f32_16x16x32_bf16(af[i], bfr[j], acc[i][j], 0, 0, 0);
      __builtin_amdgcn_s_setprio(0);
    }
    __syncthreads();
  }
#pragma unroll
  for (int i = 0; i < 4; ++i)
#pragma unroll
    for (int j = 0; j < 4; ++j) {
      int n = bn + wc * 64 + j * 16 + l15;
      float bv = bias[n];
      int which = n >> 10, d = n & 1023;
      int h = d >> 6, dk = d & 63;
#pragma unroll
      for (int r = 0; r < 4; ++r) {
        int m = bm + wr * 64 + i * 16 + lg * 4 + r;
        int b = m >> 11, t = m & 2047;
        float v = acc[i][j][r] + bv;
        int bh = b * N_HEADS + h;
        if (which == 0)      qb[((size_t)bh * T_SEQ + t) * D_HEAD + dk] = (__bf16)v;
        else if (which == 1) kb[((size_t)bh * T_SEQ + t) * D_HEAD + dk] = (__bf16)v;
        else                 vtb[((size_t)bh * D_HEAD + dk) * T_SEQ + t] = (__bf16)v;
      }
    }
}

// ---------------- output GEMM (m97 structure) ----------------
__global__ __launch_bounds__(256) void gemm_out(
    const __bf16* __restrict__ A, const __bf16* __restrict__ W,
    const float* __restrict__ bias, float* __restrict__ out) {
  __shared__ __bf16 As[128 * 64];
  __shared__ __bf16 Bs[128 * 64];
  const int bm = blockIdx.y * 128, bn = blockIdx.x * 128;
  const int tid = threadIdx.x;
  const int w = tid >> 6, l = tid & 63;
  const int wr = w >> 1, wc = w & 1;
  const int l15 = l & 15, lg = l >> 4;
  const int srow = w * 32 + (l >> 3);
  const int scol = (l & 7) * 8;
  f32x4 acc[4][4] = {};
  for (int k0 = 0; k0 < K_DIM; k0 += 64) {
#pragma unroll
    for (int q = 0; q < 4; ++q) {
      GLOAD_LDS16(&A[(size_t)(bm + srow + q * 8) * K_DIM + k0 + scol], &As[(w * 32 + q * 8) * 64]);
      GLOAD_LDS16(&W[(size_t)(bn + srow + q * 8) * K_DIM + k0 + scol], &Bs[(w * 32 + q * 8) * 64]);
    }
    __syncthreads();
#pragma unroll
    for (int kk = 0; kk < 2; ++kk) {
      bf16x8 af[4], bfr[4];
#pragma unroll
      for (int i = 0; i < 4; ++i)
        af[i] = *reinterpret_cast<const bf16x8*>(&As[(wr * 64 + i * 16 + l15) * 64 + kk * 32 + lg * 8]);
#pragma unroll
      for (int j = 0; j < 4; ++j)
        bfr[j] = *reinterpret_cast<const bf16x8*>(&Bs[(wc * 64 + j * 16 + l15) * 64 + kk * 32 + lg * 8]);
      __builtin_amdgcn_s_setprio(1);
#pragma unroll
      for (int i = 0; i < 4; ++i)
#pragma unroll
        for (int j = 0; j < 4; ++j)
          acc[i][j] = __builtin_amdgcn_mfma_f32_16x16x32_bf16(af[i], bfr[j], acc[i][j], 0, 0, 0);
      __builtin_amdgcn_s_setprio(0);
    }
    __syncthreads();
  }
#pragma unroll
  for (int i = 0; i < 4; ++i)
#pragma unroll
    for (int j = 0; j < 4; ++j) {
      int n = bn + wc * 64 + j * 16 + l15;
      float bv = bias[n];
#pragma unroll
      for (int r = 0; r < 4; ++r) {
        int m = bm + wr * 64 + i * 16 + lg * 4 + r;
        out[(size_t)m * D_MODEL + n] = acc[i][j][r] + bv;
      }
    }
}

// ---------------- in-place RoPE on q,k (BH,T,DK) ----------------
__global__ __launch_bounds__(256) void rope_qk(__bf16* __restrict__ qb, __bf16* __restrict__ kb,
                                               const float* __restrict__ fc,
                                               const float* __restrict__ fs) {
  int idx = blockIdx.x * 256 + threadIdx.x;  // pair id
  int i = idx & 31;
  int t = (idx >> 5) & (T_SEQ - 1);
  float c = fc[t * 32 + i], s = fs[t * 32 + i];
  bf16x2* qp = reinterpret_cast<bf16x2*>(qb);
  bf16x2* kp = reinterpret_cast<bf16x2*>(kb);
  bf16x2 qv = qp[idx];
  float qre = (float)qv[0], qim = (float)qv[1];
  qv[0] = (__bf16)(qre * c - qim * s);
  qv[1] = (__bf16)(qre * s + qim * c);
  qp[idx] = qv;
  bf16x2 kv = kp[idx];
  float kre = (float)kv[0], kim = (float)kv[1];
  kv[0] = (__bf16)(kre * c - kim * s);
  kv[1] = (__bf16)(kre * s + kim * c);
  kp[idx] = kv;
}

// ---------------- causal flash attention, paired q-tiles ----------------
// 1D grid of 512 blocks; XCD-chunked decode. Block handles q-tiles p and 31-p
// of head bh -> every block does exactly 33 KV-tile visits (load balanced).
// 4 waves; wave w owns q rows [q0+16w, q0+16w+16) of BOTH tiles.
// K/V staged once per KV tile via global_load_lds (linear LDS dest,
// inverse-XOR-swizzled global source), reads XOR-swizzled (conflict-free).
__global__ __launch_bounds__(256) void attn_fwd(
    const __bf16* __restrict__ qb, const __bf16* __restrict__ kb,
    const __bf16* __restrict__ vtb, __bf16* __restrict__ ob) {
  __shared__ __bf16 Ks[64 * 64];      // [key][dk], 16B chunks XOR-permuted by row&7
  __shared__ __bf16 Vs[64 * 64];      // [dk][key], same swizzle
  __shared__ __bf16 Ps[4][16][72];    // per-wave P tile [qrow][key], stride 144B
  const int g = blockIdx.x;
  const int wg = (g & 7) * 64 + (g >> 3);   // same bh stays on one XCD's L2
  const int bh = wg >> 4, p = wg & 15;
  const int q0A = p * 64, q0B = (NT - 1 - p) * 64;
  const int tid = threadIdx.x;
  const int w = tid >> 6, l = tid & 63;
  const int l15 = l & 15, lg = l >> 4;
  const int qbA = q0A + w * 16, qbB = q0B + w * 16;
  const int r8 = l >> 3, c8 = l & 7;
  const int csw = (c8 ^ r8) * 8;   // pre-swizzled global 16B-chunk offset

  bf16x8 aqA[2], aqB[2];
  {
    const __bf16* qp = qb + ((size_t)bh * T_SEQ + qbA + l15) * D_HEAD;
    aqA[0] = *reinterpret_cast<const bf16x8*>(qp + lg * 8);
    aqA[1] = *reinterpret_cast<const bf16x8*>(qp + 32 + lg * 8);
  }
  {
    const __bf16* qp = qb + ((size_t)bh * T_SEQ + qbB + l15) * D_HEAD;
    aqB[0] = *reinterpret_cast<const bf16x8*>(qp + lg * 8);
    aqB[1] = *reinterpret_cast<const bf16x8*>(qp + 32 + lg * 8);
  }
  f32x4 oA[4] = {}, oB[4] = {};
  float mA[4] = {MASKVAL, MASKVAL, MASKVAL, MASKVAL};
  float mB[4] = {MASKVAL, MASKVAL, MASKVAL, MASKVAL};
  float lA[4] = {}, lB[4] = {};

  bf16x8 kf[2][4], vf[2][4];

  auto tile = [&](const bf16x8* aq, f32x4* o, float* m, float* lsum, int qb0, int t0) {
    f32x4 s[4] = {};
    __builtin_amdgcn_s_setprio(1);
#pragma unroll
    for (int kk = 0; kk < 2; ++kk)
#pragma unroll
      for (int cb = 0; cb < 4; ++cb)
        s[cb] = __builtin_amdgcn_mfma_f32_16x16x32_bf16(aq[kk], kf[kk][cb], s[cb], 0, 0, 0);
    __builtin_amdgcn_s_setprio(0);

    float pm[4][4], rmax[4], rsum[4];
    const bool needmask = (t0 + 63 > qb0);  // wave-uniform
    if (needmask) {
#pragma unroll
      for (int r = 0; r < 4; ++r) {
        int qrow = qb0 + lg * 4 + r;
        float mx = MASKVAL;
#pragma unroll
        for (int cb = 0; cb < 4; ++cb) {
          float v = s[cb][r] * SCL_LOG2;
          v = (t0 + cb * 16 + l15 <= qrow) ? v : MASKVAL;
          pm[cb][r] = v;
          mx = fmaxf(mx, v);
        }
        rmax[r] = mx;
      }
    } else {
#pragma unroll
      for (int r = 0; r < 4; ++r) {
        float mx = MASKVAL;
#pragma unroll
        for (int cb = 0; cb < 4; ++cb) {
          float v = s[cb][r] * SCL_LOG2;
          pm[cb][r] = v;
          mx = fmaxf(mx, v);
        }
        rmax[r] = mx;
      }
    }
#pragma unroll
    for (int d = 1; d < 16; d <<= 1)
#pragma unroll
      for (int r = 0; r < 4; ++r)
        rmax[r] = fmaxf(rmax[r], __shfl_xor(rmax[r], d));
    float fac[4];
#pragma unroll
    for (int r = 0; r < 4; ++r) {
      float mnew = fmaxf(m[r], rmax[r]);
      fac[r] = __builtin_amdgcn_exp2f(m[r] - mnew);
      m[r] = mnew;
      float sum = 0.f;
#pragma unroll
      for (int cb = 0; cb < 4; ++cb) {
        float pv = __builtin_amdgcn_exp2f(pm[cb][r] - mnew);
        pm[cb][r] = pv;
        sum += pv;
      }
      rsum[r] = sum;
    }
#pragma unroll
    for (int d = 1; d < 16; d <<= 1)
#pragma unroll
      for (int r = 0; r < 4; ++r)
        rsum[r] += __shfl_xor(rsum[r], d);
#pragma unroll
    for (int r = 0; r < 4; ++r)
      lsum[r] = lsum[r] * fac[r] + rsum[r];
#pragma unroll
    for (int db = 0; db < 4; ++db)
#pragma unroll
      for (int r = 0; r < 4; ++r)
        o[db][r] *= fac[r];
    // P -> LDS (per-wave buffer; same-wave lgkmcnt ordering, no barrier)
#pragma unroll
    for (int cb = 0; cb < 4; ++cb)
#pragma unroll
      for (int r = 0; r < 4; ++r)
        Ps[w][lg * 4 + r][cb * 16 + l15] = (__bf16)pm[cb][r];
    __builtin_amdgcn_s_setprio(1);
#pragma unroll
    for (int kk = 0; kk < 2; ++kk) {
      bf16x8 af = *reinterpret_cast<const bf16x8*>(&Ps[w][l15][kk * 32 + lg * 8]);
#pragma unroll
      for (int db = 0; db < 4; ++db)
        o[db] = __builtin_amdgcn_mfma_f32_16x16x32_bf16(af, vf[kk][db], o[db], 0, 0, 0);
    }
    __builtin_amdgcn_s_setprio(0);
  };

  for (int t0 = 0; t0 <= q0B; t0 += 64) {
    // stage K (rows=key) and V (rows=dk) with inverse-swizzled source
#pragma unroll
    for (int q = 0; q < 2; ++q) {
      int row = w * 16 + q * 8 + r8;
      GLOAD_LDS16(&kb[((size_t)bh * T_SEQ + t0 + row) * D_HEAD + csw], &Ks[(w * 16 + q * 8) * 64]);
      GLOAD_LDS16(&vtb[((size_t)bh * D_HEAD + row) * T_SEQ + t0 + csw], &Vs[(w * 16 + q * 8) * 64]);
    }
    __syncthreads();
    // read K/V fragments once (swizzled reads, conflict-free), reuse for both tiles
#pragma unroll
    for (int kk = 0; kk < 2; ++kk)
#pragma unroll
      for (int cb = 0; cb < 4; ++cb) {
        int row = cb * 16 + l15;
        int col = (kk * 32 + lg * 8) ^ ((row & 7) << 3);
        kf[kk][cb] = *reinterpret_cast<const bf16x8*>(&Ks[row * 64 + col]);
        vf[kk][cb] = *reinterpret_cast<const bf16x8*>(&Vs[row * 64 + col]);
      }
    tile(aqB, oB, mB, lB, qbB, t0);
    if (t0 <= q0A) tile(aqA, oA, mA, lA, qbA, t0);
    __syncthreads();
  }

  const int b = bh >> 4, h = bh & 15;
#pragma unroll
  for (int db = 0; db < 4; ++db)
#pragma unroll
    for (int r = 0; r < 4; ++r) {
      int col = h * 64 + db * 16 + l15;
      int tA = qbA + lg * 4 + r;
      ob[((size_t)b * T_SEQ + tA) * D_MODEL + col] = (__bf16)(oA[db][r] / lA[r]);
      int tB = qbB + lg * 4 + r;
      ob[((size_t)b * T_SEQ + tB) * D_MODEL + col] = (__bf16)(oB[db][r] / lB[r]);
    }
}

extern "C" void kernel_launch(void* const* d_in, const int* in_sizes, int n_in,
                              void* d_out, int out_size, void* d_ws, size_t ws_size,
                              hipStream_t stream) {
  const float* x     = (const float*)d_in[0];
  const float* w_qkv = (const float*)d_in[1];
  const float* b_qkv = (const float*)d_in[2];
  const float* w_out = (const float*)d_in[3];
  const float* b_out = (const float*)d_in[4];
  const float* fc    = (const float*)d_in[5];
  const float* fs    = (const float*)d_in[6];
  float* out = (float*)d_out;
  char* ws = (char*)d_ws;

  __bf16* xb    = (__bf16*)(ws);
  __bf16* wqkvb = (__bf16*)(ws + 8388608);
  __bf16* woutb = (__bf16*)(ws + 14680064);
  __bf16* qbuf  = (__bf16*)(ws + 16777216);
  __bf16* kbuf  = (__bf16*)(ws + 25165824);
  __bf16* vtbuf = (__bf16*)(ws + 33554432);
  __bf16* attnb = xb;  // xb dead after gemm_qkv

  cvt_f32_bf16<<<4096, 256, 0, stream>>>(x, xb, 1048576);
  cvt_f32_bf16<<<3072, 256, 0, stream>>>(w_qkv, wqkvb, 786432);
  cvt_f32_bf16<<<1024, 256, 0, stream>>>(w_out, woutb, 262144);
  gemm_qkv<<<dim3(24, 32), 256, 0, stream>>>(xb, wqkvb, b_qkv, qbuf, kbuf, vtbuf);
  rope_qk<<<8192, 256, 0, stream>>>(qbuf, kbuf, fc, fs);
  attn_fwd<<<512, 256, 0, stream>>>(qbuf, kbuf, vtbuf, attnb);
  gemm_out<<<dim3(8, 32), 256, 0, stream>>>(attnb, woutb, b_out, out);
}